// Round 1
// baseline (860.514 us; speedup 1.0000x reference)
//
#include <hip/hip_runtime.h>
#include <math.h>

#define NBATCH 4
#define NPTS   8192
#define KNN    8
#define NCH    4096
#define QPB    128   // queries per block in cont kernel

// ws layout (doubles): [0]=recon_sum [1]=percep_sum [2]=cont_sum [3]=bnd_sum [4]=bnd_cnt

__global__ void init_ws(double* acc) {
    int t = threadIdx.x;
    if (t < 8) acc[t] = 0.0;
}

__global__ __launch_bounds__(256) void mse_kernel(const float* __restrict__ a,
                                                  const float* __restrict__ b,
                                                  int n, double* __restrict__ acc) {
    float s = 0.f;
    for (int i = blockIdx.x * 256 + threadIdx.x; i < n; i += gridDim.x * 256) {
        float d = a[i] - b[i];
        s += d * d;
    }
    __shared__ float red[256];
    red[threadIdx.x] = s;
    __syncthreads();
    if (threadIdx.x == 0) {
        double bs = 0.0;
        for (int i = 0; i < 256; ++i) bs += (double)red[i];
        atomicAdd(acc, bs);
    }
}

// Continuity: each block handles QPB=128 queries of one batch.
// 256 threads = 2 segments x 128 queries; seg 0 scans j in [0,4096), seg 1 scans [4096,8192).
// Points staged in LDS tiles of 2048 (two tiles live: one per segment half).
__global__ __launch_bounds__(256) void cont_kernel(const float* __restrict__ pts,
                                                   double* __restrict__ acc) {
    __shared__ float tile[2][2048 * 3];   // 48 KB
    __shared__ float mrgd[QPB][KNN];      // 4 KB
    __shared__ int   mrgi[QPB][KNN];      // 4 KB
    __shared__ float sred[QPB];

    const int blocksPerBatch = NPTS / QPB;            // 64
    const int b  = blockIdx.x / blocksPerBatch;
    const int q0 = (blockIdx.x % blocksPerBatch) * QPB;
    const int t  = threadIdx.x;
    const int q  = t & (QPB - 1);
    const int seg = t >> 7;                           // 0 or 1
    const int qi = q0 + q;
    const float* __restrict__ P = pts + (size_t)b * NPTS * 3;

    const float qx = P[qi * 3 + 0];
    const float qy = P[qi * 3 + 1];
    const float qz = P[qi * 3 + 2];

    float bd[KNN];
    int   bi[KNN];
#pragma unroll
    for (int s = 0; s < KNN; ++s) { bd[s] = 3.0e38f; bi[s] = -1; }

    for (int ts = 0; ts < 2; ++ts) {
        __syncthreads();   // protect previous tile from overwrite while in use
        for (int i = t; i < 2048 * 3; i += 256) {
            tile[0][i] = P[ts * 2048 * 3 + i];
            tile[1][i] = P[(4096 + ts * 2048) * 3 + i];
        }
        __syncthreads();
        const float* __restrict__ T = tile[seg];
        const int jbase = seg * 4096 + ts * 2048;
        for (int jj = 0; jj < 2048; ++jj) {
            float dx = T[jj * 3 + 0] - qx;
            float dy = T[jj * 3 + 1] - qy;
            float dz = T[jj * 3 + 2] - qz;
            float d2 = dx * dx + dy * dy + dz * dz;
            const int j = jbase + jj;
            if (j == qi) d2 = 3.0e38f;                 // exclude self
            if (d2 < bd[KNN - 1]) {
                float dcur = d2; int icur = j;
#pragma unroll
                for (int s = 0; s < KNN; ++s) {        // stable sorted insert (strict <)
                    if (dcur < bd[s]) {
                        float td = bd[s]; bd[s] = dcur; dcur = td;
                        int   ti = bi[s]; bi[s] = icur; icur = ti;
                    }
                }
            }
        }
    }

    // merge seg1's top-8 into seg0's (high-half indices are all larger -> strict < keeps
    // jax top_k's lower-index-first tie order)
    if (seg == 1) {
#pragma unroll
        for (int s = 0; s < KNN; ++s) { mrgd[q][s] = bd[s]; mrgi[q][s] = bi[s]; }
    }
    __syncthreads();
    if (seg == 0) {
#pragma unroll
        for (int s = 0; s < KNN; ++s) {
            float dcur = mrgd[q][s]; int icur = mrgi[q][s];
#pragma unroll
            for (int u = 0; u < KNN; ++u) {
                if (dcur < bd[u]) {
                    float td = bd[u]; bd[u] = dcur; dcur = td;
                    int   ti = bi[u]; bi[u] = icur; icur = ti;
                }
            }
        }
        // gather the 8 neighbor points, centroid, sum of squared deviations
        float px[KNN], py[KNN], pz[KNN];
        float sx = 0.f, sy = 0.f, sz = 0.f;
#pragma unroll
        for (int s = 0; s < KNN; ++s) {
            const int j = bi[s];
            px[s] = P[j * 3 + 0]; py[s] = P[j * 3 + 1]; pz[s] = P[j * 3 + 2];
            sx += px[s]; sy += py[s]; sz += pz[s];
        }
        const float cx = sx * (1.f / KNN), cy = sy * (1.f / KNN), cz = sz * (1.f / KNN);
        float ssum = 0.f;
#pragma unroll
        for (int s = 0; s < KNN; ++s) {
            float dx = px[s] - cx, dy = py[s] - cy, dz = pz[s] - cz;
            ssum += dx * dx + dy * dy + dz * dz;
        }
        sred[q] = ssum;
    }
    __syncthreads();
    if (t == 0) {
        double bs = 0.0;
        for (int i = 0; i < QPB; ++i) bs += (double)sred[i];
        atomicAdd(&acc[2], bs);
    }
}

// Boundary: block = 32 queries x 8 segments of 512 j's; chunk2 fully in LDS.
__global__ __launch_bounds__(256) void bnd_kernel(const float* __restrict__ c1,
                                                  const float* __restrict__ c2,
                                                  double* __restrict__ acc) {
    __shared__ float p2[NCH * 3];   // 48 KB
    const int t = threadIdx.x;
    for (int i = t; i < NCH * 3; i += 256) p2[i] = c2[i];
    __syncthreads();

    const int q   = t & 31;
    const int seg = t >> 5;                 // 0..7
    const int qi  = blockIdx.x * 32 + q;
    const float qx = c1[qi * 3 + 0];
    const float qy = c1[qi * 3 + 1];
    const float qz = c1[qi * 3 + 2];

    float m2 = 3.0e38f;
    const int j0 = seg * 512;
    for (int jj = j0; jj < j0 + 512; ++jj) {
        float dx = p2[jj * 3 + 0] - qx;
        float dy = p2[jj * 3 + 1] - qy;
        float dz = p2[jj * 3 + 2] - qz;
        float d2 = dx * dx + dy * dy + dz * dz;
        m2 = fminf(m2, d2);
    }
    __shared__ float mred[256];
    mred[t] = m2;
    __syncthreads();
    if (t < 32) {
        float mm = mred[t];
#pragma unroll
        for (int s = 1; s < 8; ++s) mm = fminf(mm, mred[t + 32 * s]);
        const float d = sqrtf(mm);
        const bool in = (d < 0.1f);
        mred[t]      = in ? d   : 0.f;
        mred[t + 32] = in ? 1.f : 0.f;
    }
    __syncthreads();
    if (t == 0) {
        double sc = 0.0, sn = 0.0;
        for (int i = 0; i < 32; ++i) { sc += (double)mred[i]; sn += (double)mred[32 + i]; }
        atomicAdd(&acc[3], sc);
        atomicAdd(&acc[4], sn);
    }
}

__global__ void fin_kernel(const double* __restrict__ acc, float* __restrict__ out) {
    if (threadIdx.x == 0) {
        const double recon  = acc[0] / (double)(NBATCH * NPTS * 3);
        const double percep = acc[1] / 4096.0;
        const double cont   = acc[2] / (double)(NBATCH * NPTS * KNN);
        const double cnt    = acc[4];
        const double bnd    = (cnt > 0.0) ? acc[3] / ((cnt > 1.0) ? cnt : 1.0) : 0.0;
        const double total  = 1.0 * recon + 0.5 * percep + 0.5 * cont + 1.0 * bnd;
        out[0] = (float)recon;
        out[1] = (float)percep;
        out[2] = (float)cont;
        out[3] = (float)bnd;
        out[4] = (float)total;
    }
}

extern "C" void kernel_launch(void* const* d_in, const int* in_sizes, int n_in,
                              void* d_out, int out_size, void* d_ws, size_t ws_size,
                              hipStream_t stream) {
    const float* pred = (const float*)d_in[0];
    const float* targ = (const float*)d_in[1];
    const float* pf   = (const float*)d_in[2];
    const float* tf   = (const float*)d_in[3];
    const float* c1   = (const float*)d_in[4];
    const float* c2   = (const float*)d_in[5];
    float* out  = (float*)d_out;
    double* acc = (double*)d_ws;

    hipLaunchKernelGGL(init_ws, dim3(1), dim3(64), 0, stream, acc);
    hipLaunchKernelGGL(mse_kernel, dim3(96), dim3(256), 0, stream,
                       pred, targ, NBATCH * NPTS * 3, &acc[0]);
    hipLaunchKernelGGL(mse_kernel, dim3(16), dim3(256), 0, stream,
                       pf, tf, NBATCH * 1024, &acc[1]);
    hipLaunchKernelGGL(cont_kernel, dim3(NBATCH * (NPTS / QPB)), dim3(256), 0, stream,
                       pred, acc);
    hipLaunchKernelGGL(bnd_kernel, dim3(NCH / 32), dim3(256), 0, stream, c1, c2, acc);
    hipLaunchKernelGGL(fin_kernel, dim3(1), dim3(64), 0, stream, acc, out);
}

// Round 2
// 228.369 us; speedup vs baseline: 3.7681x; 3.7681x over previous
//
#include <hip/hip_runtime.h>
#include <math.h>

#define NBATCH 4
#define NPTS   8192
#define KNN    8
#define NCH    4096
#define QPB    32    // queries per block in cont kernel
#define NSEG   8     // j-range segments per block
#define TILE   256   // points per segment per tile-step

// ws layout (doubles): [0]=recon_sum [1]=percep_sum [2]=cont_sum [3]=bnd_sum [4]=bnd_cnt

__device__ __forceinline__ unsigned umin32(unsigned a, unsigned b) { return a < b ? a : b; }
__device__ __forceinline__ unsigned umax32(unsigned a, unsigned b) { return a > b ? a : b; }

__global__ void init_ws(double* acc) {
    int t = threadIdx.x;
    if (t < 8) acc[t] = 0.0;
}

__global__ __launch_bounds__(256) void mse_kernel(const float* __restrict__ a,
                                                  const float* __restrict__ b,
                                                  int n, double* __restrict__ acc) {
    float s = 0.f;
    for (int i = blockIdx.x * 256 + threadIdx.x; i < n; i += gridDim.x * 256) {
        float d = a[i] - b[i];
        s += d * d;
    }
    __shared__ float red[256];
    red[threadIdx.x] = s;
    __syncthreads();
    if (threadIdx.x == 0) {
        double bs = 0.0;
        for (int i = 0; i < 256; ++i) bs += (double)red[i];
        atomicAdd(acc, bs);
    }
}

// Continuity kNN: block = 32 queries x 8 segments. Each thread scans its
// segment's 1024 j's (4 tile-steps of 256 pts staged in LDS), maintaining a
// branchless top-8 of packed keys (d2_quant | idx). Partials merged via LDS.
__global__ __launch_bounds__(256) void cont_kernel(const float* __restrict__ pts,
                                                   double* __restrict__ acc) {
    __shared__ float tile[NSEG][TILE * 3];          // 24 KB
    __shared__ unsigned mrg[NSEG][KNN][QPB];        // 8 KB, [seg][slot][q] = conflict-free
    __shared__ float sred[QPB];

    const int blocksPerBatch = NPTS / QPB;          // 256
    const int b  = blockIdx.x / blocksPerBatch;
    const int q0 = (blockIdx.x % blocksPerBatch) * QPB;
    const int t  = threadIdx.x;
    const int q  = t & (QPB - 1);
    const int seg = t >> 5;                         // 0..7
    const int qi = q0 + q;
    const float* __restrict__ P = pts + (size_t)b * NPTS * 3;

    const float qx = P[qi * 3 + 0];
    const float qy = P[qi * 3 + 1];
    const float qz = P[qi * 3 + 2];

    unsigned bd[KNN];
#pragma unroll
    for (int s = 0; s < KNN; ++s) bd[s] = 0xFFFFFFFFu;

    for (int ts = 0; ts < NPTS / NSEG / TILE; ++ts) {   // 4 steps
        __syncthreads();
        // stage all 8 segments' current 256-pt chunks: 1536 float4s, 6/thread
#pragma unroll
        for (int r = 0; r < 6; ++r) {
            const int f  = t + 256 * r;             // float4 index 0..1535
            const int s  = f / 192;                 // 192 float4 per segment
            const int k4 = f - s * 192;
            const float4 v = *reinterpret_cast<const float4*>(
                P + (s * (NPTS / NSEG) + ts * TILE) * 3 + k4 * 4);
            *reinterpret_cast<float4*>(&tile[s][k4 * 4]) = v;
        }
        __syncthreads();
        const float* __restrict__ T = tile[seg];
        const int jbase = seg * (NPTS / NSEG) + ts * TILE;
#pragma unroll 4
        for (int jj = 0; jj < TILE; ++jj) {
            const float dx = T[jj * 3 + 0] - qx;
            const float dy = T[jj * 3 + 1] - qy;
            const float dz = T[jj * 3 + 2] - qz;
            const float d2 = dx * dx + dy * dy + dz * dz;
            const int j = jbase + jj;
            unsigned key = (__float_as_uint(d2) & 0xFFFFE000u) | (unsigned)j;
            key = (j == qi) ? 0xFFFFFFFFu : key;    // exclude self
#pragma unroll
            for (int s = 0; s < KNN; ++s) {         // branchless sorted top-8
                const unsigned lo = umin32(bd[s], key);
                const unsigned hi = umax32(bd[s], key);
                bd[s] = lo; key = hi;
            }
        }
    }

    // publish partials
#pragma unroll
    for (int s = 0; s < KNN; ++s) mrg[seg][s][q] = bd[s];
    __syncthreads();

    if (t < QPB) {   // one merge thread per query
        unsigned best[KNN];
#pragma unroll
        for (int s = 0; s < KNN; ++s) best[s] = 0xFFFFFFFFu;
        for (int sg = 0; sg < NSEG; ++sg) {
#pragma unroll
            for (int u = 0; u < KNN; ++u) {
                unsigned key = mrg[sg][u][t];
#pragma unroll
                for (int s = 0; s < KNN; ++s) {
                    const unsigned lo = umin32(best[s], key);
                    const unsigned hi = umax32(best[s], key);
                    best[s] = lo; key = hi;
                }
            }
        }
        // gather neighbors, centroid, squared deviations
        float px[KNN], py[KNN], pz[KNN];
        float sx = 0.f, sy = 0.f, sz = 0.f;
#pragma unroll
        for (int s = 0; s < KNN; ++s) {
            const int j = (int)(best[s] & 0x1FFFu);
            px[s] = P[j * 3 + 0]; py[s] = P[j * 3 + 1]; pz[s] = P[j * 3 + 2];
            sx += px[s]; sy += py[s]; sz += pz[s];
        }
        const float cx = sx * (1.f / KNN), cy = sy * (1.f / KNN), cz = sz * (1.f / KNN);
        float ssum = 0.f;
#pragma unroll
        for (int s = 0; s < KNN; ++s) {
            const float dx = px[s] - cx, dy = py[s] - cy, dz = pz[s] - cz;
            ssum += dx * dx + dy * dy + dz * dz;
        }
        sred[t] = ssum;
    }
    __syncthreads();
    if (t == 0) {
        double bs = 0.0;
        for (int i = 0; i < QPB; ++i) bs += (double)sred[i];
        atomicAdd(&acc[2], bs);
    }
}

// Boundary: block = 32 queries x 8 segments of 512 j's; chunk2 fully in LDS.
__global__ __launch_bounds__(256) void bnd_kernel(const float* __restrict__ c1,
                                                  const float* __restrict__ c2,
                                                  double* __restrict__ acc) {
    __shared__ float p2[NCH * 3];   // 48 KB
    const int t = threadIdx.x;
    for (int i = t; i < NCH * 3; i += 256) p2[i] = c2[i];
    __syncthreads();

    const int q   = t & 31;
    const int seg = t >> 5;                 // 0..7
    const int qi  = blockIdx.x * 32 + q;
    const float qx = c1[qi * 3 + 0];
    const float qy = c1[qi * 3 + 1];
    const float qz = c1[qi * 3 + 2];

    float m2 = 3.0e38f;
    const int j0 = seg * 512;
#pragma unroll 4
    for (int jj = j0; jj < j0 + 512; ++jj) {
        const float dx = p2[jj * 3 + 0] - qx;
        const float dy = p2[jj * 3 + 1] - qy;
        const float dz = p2[jj * 3 + 2] - qz;
        const float d2 = dx * dx + dy * dy + dz * dz;
        m2 = fminf(m2, d2);
    }
    __shared__ float mred[256];
    mred[t] = m2;
    __syncthreads();
    if (t < 32) {
        float mm = mred[t];
#pragma unroll
        for (int s = 1; s < 8; ++s) mm = fminf(mm, mred[t + 32 * s]);
        const float d = sqrtf(mm);
        const bool in = (d < 0.1f);
        mred[t]      = in ? d   : 0.f;
        mred[t + 32] = in ? 1.f : 0.f;
    }
    __syncthreads();
    if (t == 0) {
        double sc = 0.0, sn = 0.0;
        for (int i = 0; i < 32; ++i) { sc += (double)mred[i]; sn += (double)mred[32 + i]; }
        atomicAdd(&acc[3], sc);
        atomicAdd(&acc[4], sn);
    }
}

__global__ void fin_kernel(const double* __restrict__ acc, float* __restrict__ out) {
    if (threadIdx.x == 0) {
        const double recon  = acc[0] / (double)(NBATCH * NPTS * 3);
        const double percep = acc[1] / 4096.0;
        const double cont   = acc[2] / (double)(NBATCH * NPTS * KNN);
        const double cnt    = acc[4];
        const double bnd    = (cnt > 0.0) ? acc[3] / ((cnt > 1.0) ? cnt : 1.0) : 0.0;
        const double total  = 1.0 * recon + 0.5 * percep + 0.5 * cont + 1.0 * bnd;
        out[0] = (float)recon;
        out[1] = (float)percep;
        out[2] = (float)cont;
        out[3] = (float)bnd;
        out[4] = (float)total;
    }
}

extern "C" void kernel_launch(void* const* d_in, const int* in_sizes, int n_in,
                              void* d_out, int out_size, void* d_ws, size_t ws_size,
                              hipStream_t stream) {
    const float* pred = (const float*)d_in[0];
    const float* targ = (const float*)d_in[1];
    const float* pf   = (const float*)d_in[2];
    const float* tf   = (const float*)d_in[3];
    const float* c1   = (const float*)d_in[4];
    const float* c2   = (const float*)d_in[5];
    float* out  = (float*)d_out;
    double* acc = (double*)d_ws;

    hipLaunchKernelGGL(init_ws, dim3(1), dim3(64), 0, stream, acc);
    hipLaunchKernelGGL(mse_kernel, dim3(96), dim3(256), 0, stream,
                       pred, targ, NBATCH * NPTS * 3, &acc[0]);
    hipLaunchKernelGGL(mse_kernel, dim3(16), dim3(256), 0, stream,
                       pf, tf, NBATCH * 1024, &acc[1]);
    hipLaunchKernelGGL(cont_kernel, dim3(NBATCH * (NPTS / QPB)), dim3(256), 0, stream,
                       pred, acc);
    hipLaunchKernelGGL(bnd_kernel, dim3(NCH / 32), dim3(256), 0, stream, c1, c2, acc);
    hipLaunchKernelGGL(fin_kernel, dim3(1), dim3(64), 0, stream, acc, out);
}

// Round 3
// 177.705 us; speedup vs baseline: 4.8424x; 1.2851x over previous
//
#include <hip/hip_runtime.h>
#include <math.h>

#define NBATCH 4
#define NPTS   8192
#define KNN    8
#define NCH    4096
#define QPB    32    // queries per block in cont kernel
#define NSEG   8     // j-range segments per block
#define TILE   128   // points per segment per tile-step
#define SEGLEN (NPTS / NSEG)          // 1024
#define NSTEP  (SEGLEN / TILE)        // 8

// ws layout (doubles): [0]=recon_sum [1]=percep_sum [2]=cont_sum [3]=bnd_sum [4]=bnd_cnt

__device__ __forceinline__ unsigned umin32(unsigned a, unsigned b) { return a < b ? a : b; }
__device__ __forceinline__ unsigned umed3(unsigned a, unsigned b, unsigned c) {
    unsigned d;
    asm("v_med3_u32 %0, %1, %2, %3" : "=v"(d) : "v"(a), "v"(b), "v"(c));
    return d;
}
// sorted-ascending top-8 insert, depth-1 (all reads from old values; descending write order)
#define INSERT8(bd, key)                              \
    do {                                              \
        bd[7] = umed3(key, bd[6], bd[7]);             \
        bd[6] = umed3(key, bd[5], bd[6]);             \
        bd[5] = umed3(key, bd[4], bd[5]);             \
        bd[4] = umed3(key, bd[3], bd[4]);             \
        bd[3] = umed3(key, bd[2], bd[3]);             \
        bd[2] = umed3(key, bd[1], bd[2]);             \
        bd[1] = umed3(key, bd[0], bd[1]);             \
        bd[0] = umin32(bd[0], key);                   \
    } while (0)

__global__ void init_ws(double* acc) {
    int t = threadIdx.x;
    if (t < 8) acc[t] = 0.0;
}

__global__ __launch_bounds__(256) void mse_kernel(const float* __restrict__ a,
                                                  const float* __restrict__ b,
                                                  int n, double* __restrict__ acc) {
    float s = 0.f;
    for (int i = blockIdx.x * 256 + threadIdx.x; i < n; i += gridDim.x * 256) {
        float d = a[i] - b[i];
        s += d * d;
    }
    __shared__ float red[256];
    red[threadIdx.x] = s;
    __syncthreads();
    if (threadIdx.x == 0) {
        double bs = 0.0;
        for (int i = 0; i < 256; ++i) bs += (double)red[i];
        atomicAdd(acc, bs);
    }
}

// Continuity kNN: block = 32 queries x 8 segments; per thread 1024 candidates in
// 8 LDS tile-steps of 128 pts. Branchless depth-1 med3 top-8. Merge via LDS.
__global__ __launch_bounds__(256) void cont_kernel(const float* __restrict__ pts,
                                                   double* __restrict__ acc) {
    // union: tile (12 KB) reused as mrg (8 KB) + sred after the scan phase
    __shared__ __align__(16) char smem[NSEG * TILE * 3 * 4];   // 12288 B
    float (*tile)[TILE * 3] = (float (*)[TILE * 3])smem;
    unsigned (*mrg)[KNN][QPB] = (unsigned (*)[KNN][QPB])smem;  // 8 KB
    float* sred = (float*)(smem + NSEG * KNN * QPB * 4);       // +128 B

    const int blocksPerBatch = NPTS / QPB;          // 256
    const int b  = blockIdx.x / blocksPerBatch;
    const int q0 = (blockIdx.x % blocksPerBatch) * QPB;
    const int t  = threadIdx.x;
    const int q  = t & (QPB - 1);
    const int seg = t >> 5;                         // 0..7
    const int qi = q0 + q;
    const float* __restrict__ P = pts + (size_t)b * NPTS * 3;

    const float qx = P[qi * 3 + 0];
    const float qy = P[qi * 3 + 1];
    const float qz = P[qi * 3 + 2];

    unsigned bd[KNN];
#pragma unroll
    for (int s = 0; s < KNN; ++s) bd[s] = 0xFFFFFFFFu;

    for (int ts = 0; ts < NSTEP; ++ts) {
        __syncthreads();
        // stage all 8 segments' current 128-pt chunks: 768 float4s, 3/thread
#pragma unroll
        for (int r = 0; r < 3; ++r) {
            const int f  = t + 256 * r;             // float4 index 0..767
            const int s  = f / (TILE * 3 / 4);      // 96 float4 per segment
            const int k4 = f - s * (TILE * 3 / 4);
            const float4 v = *reinterpret_cast<const float4*>(
                P + (s * SEGLEN + ts * TILE) * 3 + k4 * 4);
            *reinterpret_cast<float4*>(&tile[s][k4 * 4]) = v;
        }
        __syncthreads();
        const float* __restrict__ T = tile[seg];
        const int jbase = seg * SEGLEN + ts * TILE;
#pragma unroll 4
        for (int jj = 0; jj < TILE; ++jj) {
            const float dx = T[jj * 3 + 0] - qx;
            const float dy = T[jj * 3 + 1] - qy;
            const float dz = T[jj * 3 + 2] - qz;
            const float d2 = dx * dx + dy * dy + dz * dz;
            const unsigned key = (__float_as_uint(d2) & 0xFFFFE000u) | (unsigned)(jbase + jj);
            INSERT8(bd, key);   // self (key==qi) filtered at merge
        }
    }

    __syncthreads();   // tile no longer needed; safe to alias as mrg
#pragma unroll
    for (int s = 0; s < KNN; ++s) mrg[seg][s][q] = bd[s];
    __syncthreads();

    if (t < QPB) {   // one merge thread per query
        const unsigned selfkey = (unsigned)qi;
        unsigned best[KNN];
#pragma unroll
        for (int s = 0; s < KNN; ++s) best[s] = 0xFFFFFFFFu;
        for (int sg = 0; sg < NSEG; ++sg) {
#pragma unroll
            for (int u = 0; u < KNN; ++u) {
                unsigned key = mrg[sg][u][t];
                key = (key == selfkey) ? 0xFFFFFFFFu : key;   // drop self
                INSERT8(best, key);
            }
        }
        // gather neighbors, centroid, squared deviations
        float px[KNN], py[KNN], pz[KNN];
        float sx = 0.f, sy = 0.f, sz = 0.f;
#pragma unroll
        for (int s = 0; s < KNN; ++s) {
            const int j = (int)(best[s] & 0x1FFFu);
            px[s] = P[j * 3 + 0]; py[s] = P[j * 3 + 1]; pz[s] = P[j * 3 + 2];
            sx += px[s]; sy += py[s]; sz += pz[s];
        }
        const float cx = sx * (1.f / KNN), cy = sy * (1.f / KNN), cz = sz * (1.f / KNN);
        float ssum = 0.f;
#pragma unroll
        for (int s = 0; s < KNN; ++s) {
            const float dx = px[s] - cx, dy = py[s] - cy, dz = pz[s] - cz;
            ssum += dx * dx + dy * dy + dz * dz;
        }
        sred[t] = ssum;
    }
    __syncthreads();
    if (t == 0) {
        double bs = 0.0;
        for (int i = 0; i < QPB; ++i) bs += (double)sred[i];
        atomicAdd(&acc[2], bs);
    }
}

// Boundary: block = 32 queries x 8 segments of 512 j's; chunk2 fully in LDS.
__global__ __launch_bounds__(256) void bnd_kernel(const float* __restrict__ c1,
                                                  const float* __restrict__ c2,
                                                  double* __restrict__ acc) {
    __shared__ float p2[NCH * 3];   // 48 KB
    const int t = threadIdx.x;
    for (int i = t; i < NCH * 3; i += 256) p2[i] = c2[i];
    __syncthreads();

    const int q   = t & 31;
    const int seg = t >> 5;                 // 0..7
    const int qi  = blockIdx.x * 32 + q;
    const float qx = c1[qi * 3 + 0];
    const float qy = c1[qi * 3 + 1];
    const float qz = c1[qi * 3 + 2];

    float m2 = 3.0e38f;
    const int j0 = seg * 512;
#pragma unroll 4
    for (int jj = j0; jj < j0 + 512; ++jj) {
        const float dx = p2[jj * 3 + 0] - qx;
        const float dy = p2[jj * 3 + 1] - qy;
        const float dz = p2[jj * 3 + 2] - qz;
        const float d2 = dx * dx + dy * dy + dz * dz;
        m2 = fminf(m2, d2);
    }
    __shared__ float mred[256];
    mred[t] = m2;
    __syncthreads();
    if (t < 32) {
        float mm = mred[t];
#pragma unroll
        for (int s = 1; s < 8; ++s) mm = fminf(mm, mred[t + 32 * s]);
        const float d = sqrtf(mm);
        const bool in = (d < 0.1f);
        mred[t]      = in ? d   : 0.f;
        mred[t + 32] = in ? 1.f : 0.f;
    }
    __syncthreads();
    if (t == 0) {
        double sc = 0.0, sn = 0.0;
        for (int i = 0; i < 32; ++i) { sc += (double)mred[i]; sn += (double)mred[32 + i]; }
        atomicAdd(&acc[3], sc);
        atomicAdd(&acc[4], sn);
    }
}

__global__ void fin_kernel(const double* __restrict__ acc, float* __restrict__ out) {
    if (threadIdx.x == 0) {
        const double recon  = acc[0] / (double)(NBATCH * NPTS * 3);
        const double percep = acc[1] / 4096.0;
        const double cont   = acc[2] / (double)(NBATCH * NPTS * KNN);
        const double cnt    = acc[4];
        const double bnd    = (cnt > 0.0) ? acc[3] / ((cnt > 1.0) ? cnt : 1.0) : 0.0;
        const double total  = 1.0 * recon + 0.5 * percep + 0.5 * cont + 1.0 * bnd;
        out[0] = (float)recon;
        out[1] = (float)percep;
        out[2] = (float)cont;
        out[3] = (float)bnd;
        out[4] = (float)total;
    }
}

extern "C" void kernel_launch(void* const* d_in, const int* in_sizes, int n_in,
                              void* d_out, int out_size, void* d_ws, size_t ws_size,
                              hipStream_t stream) {
    const float* pred = (const float*)d_in[0];
    const float* targ = (const float*)d_in[1];
    const float* pf   = (const float*)d_in[2];
    const float* tf   = (const float*)d_in[3];
    const float* c1   = (const float*)d_in[4];
    const float* c2   = (const float*)d_in[5];
    float* out  = (float*)d_out;
    double* acc = (double*)d_ws;

    hipLaunchKernelGGL(init_ws, dim3(1), dim3(64), 0, stream, acc);
    hipLaunchKernelGGL(mse_kernel, dim3(96), dim3(256), 0, stream,
                       pred, targ, NBATCH * NPTS * 3, &acc[0]);
    hipLaunchKernelGGL(mse_kernel, dim3(16), dim3(256), 0, stream,
                       pf, tf, NBATCH * 1024, &acc[1]);
    hipLaunchKernelGGL(cont_kernel, dim3(NBATCH * (NPTS / QPB)), dim3(256), 0, stream,
                       pred, acc);
    hipLaunchKernelGGL(bnd_kernel, dim3(NCH / 32), dim3(256), 0, stream, c1, c2, acc);
    hipLaunchKernelGGL(fin_kernel, dim3(1), dim3(64), 0, stream, acc, out);
}

// Round 4
// 164.772 us; speedup vs baseline: 5.2224x; 1.0785x over previous
//
#include <hip/hip_runtime.h>
#include <math.h>

#define NBATCH 4
#define NPTS   8192
#define KNN    8
#define NCH    4096
#define QPB    16    // queries per block in cont kernel
#define NSEG   16    // j-range segments per block
#define TILE   64    // points per segment per tile-step
#define SEGLEN (NPTS / NSEG)          // 512
#define NSTEP  (SEGLEN / TILE)        // 8

// ws layout (doubles): [0]=recon_sum [1]=percep_sum [2]=cont_sum [3]=bnd_sum [4]=bnd_cnt

__device__ __forceinline__ unsigned umin32(unsigned a, unsigned b) { return a < b ? a : b; }
__device__ __forceinline__ unsigned umed3(unsigned a, unsigned b, unsigned c) {
    unsigned d;
    asm("v_med3_u32 %0, %1, %2, %3" : "=v"(d) : "v"(a), "v"(b), "v"(c));
    return d;
}
// sorted-ascending top-8 insert, depth-1 (all reads from old values; descending write order)
#define INSERT8(bd, key)                              \
    do {                                              \
        bd[7] = umed3(key, bd[6], bd[7]);             \
        bd[6] = umed3(key, bd[5], bd[6]);             \
        bd[5] = umed3(key, bd[4], bd[5]);             \
        bd[4] = umed3(key, bd[3], bd[4]);             \
        bd[3] = umed3(key, bd[2], bd[3]);             \
        bd[2] = umed3(key, bd[1], bd[2]);             \
        bd[1] = umed3(key, bd[0], bd[1]);             \
        bd[0] = umin32(bd[0], key);                   \
    } while (0)

__global__ void init_ws(double* acc) {
    int t = threadIdx.x;
    if (t < 8) acc[t] = 0.0;
}

__global__ __launch_bounds__(256) void mse_kernel(const float* __restrict__ a,
                                                  const float* __restrict__ b,
                                                  int n, double* __restrict__ acc) {
    float s = 0.f;
    for (int i = blockIdx.x * 256 + threadIdx.x; i < n; i += gridDim.x * 256) {
        float d = a[i] - b[i];
        s += d * d;
    }
    __shared__ float red[256];
    red[threadIdx.x] = s;
    __syncthreads();
    if (threadIdx.x == 0) {
        double bs = 0.0;
        for (int i = 0; i < 256; ++i) bs += (double)red[i];
        atomicAdd(acc, bs);
    }
}

// Continuity kNN: block = 16 queries x 16 segments; per thread 512 candidates in
// 8 LDS tile-steps of 64 float4 points (x,y,z,|p|^2). Key = |p|^2-2p.q+|q|^2+eps
// (monotone in d^2, positive). Branchless depth-1 med3 top-8. Merge via LDS.
__global__ __launch_bounds__(256) void cont_kernel(const float* __restrict__ pts,
                                                   double* __restrict__ acc) {
    // tile4 (16.6 KB) aliased after scan as mrg (8 KB) + sred
    __shared__ __align__(16) char smem[NSEG * (TILE + 1) * 16];   // 16640 B
    float4 (*tile4)[TILE + 1] = (float4 (*)[TILE + 1])smem;       // row stride 1040 B
    unsigned (*mrg)[KNN][QPB] = (unsigned (*)[KNN][QPB])smem;     // 8192 B
    float* sred = (float*)(smem + NSEG * KNN * QPB * 4);          // +64 B

    const int blocksPerBatch = NPTS / QPB;          // 512
    const int b  = blockIdx.x / blocksPerBatch;
    const int q0 = (blockIdx.x % blocksPerBatch) * QPB;
    const int t  = threadIdx.x;
    const int q  = t & (QPB - 1);
    const int seg = t >> 4;                         // 0..15
    const int qi = q0 + q;
    const float* __restrict__ P = pts + (size_t)b * NPTS * 3;

    const float qx = P[qi * 3 + 0];
    const float qy = P[qi * 3 + 1];
    const float qz = P[qi * 3 + 2];
    const float m2x = -2.f * qx, m2y = -2.f * qy, m2z = -2.f * qz;
    const float qnp = qx * qx + qy * qy + qz * qz + 1e-6f;   // keeps key > 0

    unsigned bd[KNN];
#pragma unroll
    for (int s = 0; s < KNN; ++s) bd[s] = 0xFFFFFFFFu;

    for (int ts = 0; ts < NSTEP; ++ts) {
        __syncthreads();
        // stage 16 segs x 64 pts as float4 (compute |p|^2 on the fly): 4 pts/thread
#pragma unroll
        for (int r = 0; r < 4; ++r) {
            const int f = t + 256 * r;              // 0..1023
            const int s = f >> 6;
            const int k = f & (TILE - 1);
            const int idx = s * SEGLEN + ts * TILE + k;
            const float x = P[idx * 3 + 0];
            const float y = P[idx * 3 + 1];
            const float z = P[idx * 3 + 2];
            const float w = x * x + y * y + z * z;
            tile4[s][k] = make_float4(x, y, z, w);
        }
        __syncthreads();
        const float4* __restrict__ T4 = tile4[seg];
        const unsigned jbase = (unsigned)(seg * SEGLEN + ts * TILE);  // multiple of 64
#pragma unroll
        for (int jj = 0; jj < TILE; ++jj) {
            const float4 c = T4[jj];
            float s1 = fmaf(c.z, m2z, c.w);
            s1 = fmaf(c.y, m2y, s1);
            s1 = fmaf(c.x, m2x, s1);
            s1 += qnp;
            const unsigned key = ((__float_as_uint(s1) & 0xFFFFE000u) | jbase) | (unsigned)jj;
            INSERT8(bd, key);   // self filtered at merge
        }
    }

    __syncthreads();   // tile no longer needed; safe to alias as mrg
#pragma unroll
    for (int s = 0; s < KNN; ++s) mrg[seg][s][q] = bd[s];
    __syncthreads();

    if (t < QPB) {   // one merge thread per query
        const unsigned selfidx = (unsigned)(q0 + t);
        unsigned best[KNN];
#pragma unroll
        for (int s = 0; s < KNN; ++s) best[s] = 0xFFFFFFFFu;
        for (int sg = 0; sg < NSEG; ++sg) {
#pragma unroll
            for (int u = 0; u < KNN; ++u) {
                unsigned key = mrg[sg][u][t];
                key = ((key & 0x1FFFu) == selfidx) ? 0xFFFFFFFFu : key;   // drop self
                INSERT8(best, key);
            }
        }
        // gather neighbors, centroid, squared deviations
        float px[KNN], py[KNN], pz[KNN];
        float sx = 0.f, sy = 0.f, sz = 0.f;
#pragma unroll
        for (int s = 0; s < KNN; ++s) {
            const int j = (int)(best[s] & 0x1FFFu);
            px[s] = P[j * 3 + 0]; py[s] = P[j * 3 + 1]; pz[s] = P[j * 3 + 2];
            sx += px[s]; sy += py[s]; sz += pz[s];
        }
        const float cx = sx * (1.f / KNN), cy = sy * (1.f / KNN), cz = sz * (1.f / KNN);
        float ssum = 0.f;
#pragma unroll
        for (int s = 0; s < KNN; ++s) {
            const float dx = px[s] - cx, dy = py[s] - cy, dz = pz[s] - cz;
            ssum += dx * dx + dy * dy + dz * dz;
        }
        sred[t] = ssum;
    }
    __syncthreads();
    if (t == 0) {
        double bs = 0.0;
        for (int i = 0; i < QPB; ++i) bs += (double)sred[i];
        atomicAdd(&acc[2], bs);
    }
}

// Boundary: block = 32 queries x 8 segments of 512 j's; chunk2 fully in LDS.
__global__ __launch_bounds__(256) void bnd_kernel(const float* __restrict__ c1,
                                                  const float* __restrict__ c2,
                                                  double* __restrict__ acc) {
    __shared__ float p2[NCH * 3];   // 48 KB
    const int t = threadIdx.x;
    for (int i = t; i < NCH * 3; i += 256) p2[i] = c2[i];
    __syncthreads();

    const int q   = t & 31;
    const int seg = t >> 5;                 // 0..7
    const int qi  = blockIdx.x * 32 + q;
    const float qx = c1[qi * 3 + 0];
    const float qy = c1[qi * 3 + 1];
    const float qz = c1[qi * 3 + 2];

    float m2 = 3.0e38f;
    const int j0 = seg * 512;
#pragma unroll 4
    for (int jj = j0; jj < j0 + 512; ++jj) {
        const float dx = p2[jj * 3 + 0] - qx;
        const float dy = p2[jj * 3 + 1] - qy;
        const float dz = p2[jj * 3 + 2] - qz;
        const float d2 = dx * dx + dy * dy + dz * dz;
        m2 = fminf(m2, d2);
    }
    __shared__ float mred[256];
    mred[t] = m2;
    __syncthreads();
    if (t < 32) {
        float mm = mred[t];
#pragma unroll
        for (int s = 1; s < 8; ++s) mm = fminf(mm, mred[t + 32 * s]);
        const float d = sqrtf(mm);
        const bool in = (d < 0.1f);
        mred[t]      = in ? d   : 0.f;
        mred[t + 32] = in ? 1.f : 0.f;
    }
    __syncthreads();
    if (t == 0) {
        double sc = 0.0, sn = 0.0;
        for (int i = 0; i < 32; ++i) { sc += (double)mred[i]; sn += (double)mred[32 + i]; }
        atomicAdd(&acc[3], sc);
        atomicAdd(&acc[4], sn);
    }
}

__global__ void fin_kernel(const double* __restrict__ acc, float* __restrict__ out) {
    if (threadIdx.x == 0) {
        const double recon  = acc[0] / (double)(NBATCH * NPTS * 3);
        const double percep = acc[1] / 4096.0;
        const double cont   = acc[2] / (double)(NBATCH * NPTS * KNN);
        const double cnt    = acc[4];
        const double bnd    = (cnt > 0.0) ? acc[3] / ((cnt > 1.0) ? cnt : 1.0) : 0.0;
        const double total  = 1.0 * recon + 0.5 * percep + 0.5 * cont + 1.0 * bnd;
        out[0] = (float)recon;
        out[1] = (float)percep;
        out[2] = (float)cont;
        out[3] = (float)bnd;
        out[4] = (float)total;
    }
}

extern "C" void kernel_launch(void* const* d_in, const int* in_sizes, int n_in,
                              void* d_out, int out_size, void* d_ws, size_t ws_size,
                              hipStream_t stream) {
    const float* pred = (const float*)d_in[0];
    const float* targ = (const float*)d_in[1];
    const float* pf   = (const float*)d_in[2];
    const float* tf   = (const float*)d_in[3];
    const float* c1   = (const float*)d_in[4];
    const float* c2   = (const float*)d_in[5];
    float* out  = (float*)d_out;
    double* acc = (double*)d_ws;

    hipLaunchKernelGGL(init_ws, dim3(1), dim3(64), 0, stream, acc);
    hipLaunchKernelGGL(mse_kernel, dim3(96), dim3(256), 0, stream,
                       pred, targ, NBATCH * NPTS * 3, &acc[0]);
    hipLaunchKernelGGL(mse_kernel, dim3(16), dim3(256), 0, stream,
                       pf, tf, NBATCH * 1024, &acc[1]);
    hipLaunchKernelGGL(cont_kernel, dim3(NBATCH * (NPTS / QPB)), dim3(256), 0, stream,
                       pred, acc);
    hipLaunchKernelGGL(bnd_kernel, dim3(NCH / 32), dim3(256), 0, stream, c1, c2, acc);
    hipLaunchKernelGGL(fin_kernel, dim3(1), dim3(64), 0, stream, acc, out);
}

// Round 5
// 161.635 us; speedup vs baseline: 5.3238x; 1.0194x over previous
//
#include <hip/hip_runtime.h>
#include <math.h>

#define NBATCH 4
#define NPTS   8192
#define KNN    8
#define NCH    4096
#define QPB    16    // queries per block in cont kernel
#define NSEG   16    // j-range segments per block
#define TILE   64    // points per segment per tile-step
#define SEGLEN (NPTS / NSEG)          // 512
#define NSTEP  (SEGLEN / TILE)        // 8

// ws layout (doubles): [0]=recon_sum [1]=percep_sum [2]=cont_sum [3]=bnd_sum [4]=bnd_cnt

// single-block insert: 8 instrs, bd pinned via tied "+v", in-place descending
// order reads only pre-block values => depth-1 sorted insert (ascending top-8).
#define INSERT8(bd, key)                                          \
    asm("v_med3_u32 %7, %8, %6, %7\n\t"                           \
        "v_med3_u32 %6, %8, %5, %6\n\t"                           \
        "v_med3_u32 %5, %8, %4, %5\n\t"                           \
        "v_med3_u32 %4, %8, %3, %4\n\t"                           \
        "v_med3_u32 %3, %8, %2, %3\n\t"                           \
        "v_med3_u32 %2, %8, %1, %2\n\t"                           \
        "v_med3_u32 %1, %8, %0, %1\n\t"                           \
        "v_min_u32  %0, %0, %8"                                   \
        : "+v"(bd[0]), "+v"(bd[1]), "+v"(bd[2]), "+v"(bd[3]),     \
          "+v"(bd[4]), "+v"(bd[5]), "+v"(bd[6]), "+v"(bd[7])      \
        : "v"(key))

// Fused MSE: blocks [0,96) -> recon (float4, 24576 exactly); [96,112) -> percep.
__global__ __launch_bounds__(256) void mse_kernel(const float* __restrict__ a,
                                                  const float* __restrict__ b,
                                                  const float* __restrict__ a2,
                                                  const float* __restrict__ b2,
                                                  double* __restrict__ acc) {
    const int t = threadIdx.x;
    const int blk = blockIdx.x;
    float s;
    int which;
    if (blk < 96) {
        which = 0;
        const int i = blk * 256 + t;
        const float4 va = reinterpret_cast<const float4*>(a)[i];
        const float4 vb = reinterpret_cast<const float4*>(b)[i];
        const float dx = va.x - vb.x, dy = va.y - vb.y;
        const float dz = va.z - vb.z, dw = va.w - vb.w;
        s = dx * dx + dy * dy + dz * dz + dw * dw;
    } else {
        which = 1;
        const int i = (blk - 96) * 256 + t;
        const float d = a2[i] - b2[i];
        s = d * d;
    }
#pragma unroll
    for (int o = 32; o > 0; o >>= 1) s += __shfl_down(s, o, 64);
    __shared__ float wsum[4];
    if ((t & 63) == 0) wsum[t >> 6] = s;
    __syncthreads();
    if (t == 0)
        atomicAdd(&acc[which], (double)(wsum[0] + wsum[1] + wsum[2] + wsum[3]));
}

// Continuity kNN: block = 16 queries x 16 segments; per thread 512 candidates in
// 8 LDS tile-steps of 64 float4 points (x,y,z,|p|^2), layout [TILE][NSEG] so the
// wave's 4 seg-groups read disjoint bank quads (conflict-free, 16 KB exact).
// Key = (|p|^2 - 2p.q + |q|^2 + eps) bits | index; branchless asm med3 top-8.
__global__ __launch_bounds__(256, 8) void cont_kernel(const float* __restrict__ pts,
                                                      double* __restrict__ acc) {
    __shared__ __align__(16) char smem[TILE * NSEG * 16];         // 16384 B
    float4 (*tile4)[NSEG] = (float4 (*)[NSEG])smem;               // [k][seg]
    unsigned (*mrg)[KNN][QPB] = (unsigned (*)[KNN][QPB])smem;     // 8192 B alias
    float* sred = (float*)(smem + NSEG * KNN * QPB * 4);          // +64 B

    const int blocksPerBatch = NPTS / QPB;          // 512
    const int b  = blockIdx.x / blocksPerBatch;
    const int q0 = (blockIdx.x % blocksPerBatch) * QPB;
    const int t  = threadIdx.x;
    const int q  = t & (QPB - 1);
    const int seg = t >> 4;                         // 0..15
    const int qi = q0 + q;
    const float* __restrict__ P = pts + (size_t)b * NPTS * 3;

    const float qx = P[qi * 3 + 0];
    const float qy = P[qi * 3 + 1];
    const float qz = P[qi * 3 + 2];
    const float m2x = -2.f * qx, m2y = -2.f * qy, m2z = -2.f * qz;
    const float qnp = qx * qx + qy * qy + qz * qz + 1e-6f;   // keeps key > 0

    unsigned bd[KNN];
#pragma unroll
    for (int s = 0; s < KNN; ++s) bd[s] = 0xFFFFFFFFu;

    for (int ts = 0; ts < NSTEP; ++ts) {
        __syncthreads();
        // stage 16 segs x 64 pts (coalesced global); write tile4[k][s]
#pragma unroll
        for (int r = 0; r < 4; ++r) {
            const int f = t + 256 * r;              // 0..1023
            const int s = f >> 6;
            const int k = f & (TILE - 1);
            const int idx = s * SEGLEN + ts * TILE + k;
            const float x = P[idx * 3 + 0];
            const float y = P[idx * 3 + 1];
            const float z = P[idx * 3 + 2];
            tile4[k][s] = make_float4(x, y, z, x * x + y * y + z * z);
        }
        __syncthreads();
        const unsigned jbase = (unsigned)(seg * SEGLEN + ts * TILE);  // bits 6..12
#pragma unroll
        for (int jj = 0; jj < TILE; ++jj) {
            const float4 c = tile4[jj][seg];
            float s1 = fmaf(c.x, m2x, qnp);
            s1 = fmaf(c.y, m2y, s1);
            s1 = fmaf(c.z, m2z, s1);
            s1 += c.w;
            // and_or(bits,mask,jbase) then or with imm jj: 2 VALU
            const unsigned key = ((__float_as_uint(s1) & 0xFFFFE000u) | jbase) | (unsigned)jj;
            INSERT8(bd, key);   // self filtered at merge
        }
    }

    __syncthreads();   // tile no longer needed; safe to alias as mrg
#pragma unroll
    for (int s = 0; s < KNN; ++s) mrg[seg][s][q] = bd[s];
    __syncthreads();

    if (t < QPB) {   // one merge thread per query
        const unsigned selfidx = (unsigned)(q0 + t);
        unsigned best[KNN];
#pragma unroll
        for (int s = 0; s < KNN; ++s) best[s] = 0xFFFFFFFFu;
        for (int sg = 0; sg < NSEG; ++sg) {
#pragma unroll
            for (int u = 0; u < KNN; ++u) {
                unsigned key = mrg[sg][u][t];
                key = ((key & 0x1FFFu) == selfidx) ? 0xFFFFFFFFu : key;   // drop self
                INSERT8(best, key);
            }
        }
        float px[KNN], py[KNN], pz[KNN];
        float sx = 0.f, sy = 0.f, sz = 0.f;
#pragma unroll
        for (int s = 0; s < KNN; ++s) {
            const int j = (int)(best[s] & 0x1FFFu);
            px[s] = P[j * 3 + 0]; py[s] = P[j * 3 + 1]; pz[s] = P[j * 3 + 2];
            sx += px[s]; sy += py[s]; sz += pz[s];
        }
        const float cx = sx * (1.f / KNN), cy = sy * (1.f / KNN), cz = sz * (1.f / KNN);
        float ssum = 0.f;
#pragma unroll
        for (int s = 0; s < KNN; ++s) {
            const float dx = px[s] - cx, dy = py[s] - cy, dz = pz[s] - cz;
            ssum += dx * dx + dy * dy + dz * dz;
        }
        sred[t] = ssum;
    }
    __syncthreads();
    if (t == 0) {
        double bs = 0.0;
        for (int i = 0; i < QPB; ++i) bs += (double)sred[i];
        atomicAdd(&acc[2], bs);
    }
}

// Boundary: grid 256 x 256 thr; 16 queries x 16 segs of 256 j's per block.
// chunk2 staged as float4 (x,y,z,|p|^2); min over (|p|^2 - 2p.q), |q|^2 added once.
// Per-seg rotated start (+2*(seg&3)) de-conflicts the 4 seg-groups' LDS reads.
__global__ __launch_bounds__(256) void bnd_kernel(const float* __restrict__ c1,
                                                  const float* __restrict__ c2,
                                                  double* __restrict__ acc) {
    __shared__ float4 p2[NCH];          // 64 KB
    __shared__ float qn_s[16];
    __shared__ float pmin[16][17];
    __shared__ float bsum[16], bcnt[16];
    const int t = threadIdx.x;
#pragma unroll
    for (int r = 0; r < 16; ++r) {
        const int idx = t + 256 * r;
        const float x = c2[idx * 3 + 0];
        const float y = c2[idx * 3 + 1];
        const float z = c2[idx * 3 + 2];
        p2[idx] = make_float4(x, y, z, x * x + y * y + z * z);
    }
    const int q   = t & 15;
    const int seg = t >> 4;
    const int qi  = blockIdx.x * 16 + q;
    const float qx = c1[qi * 3 + 0];
    const float qy = c1[qi * 3 + 1];
    const float qz = c1[qi * 3 + 2];
    const float m2x = -2.f * qx, m2y = -2.f * qy, m2z = -2.f * qz;
    if (seg == 0) qn_s[q] = qx * qx + qy * qy + qz * qz;
    __syncthreads();

    float m = 3.0e38f;
    const int j0  = seg * (NCH / 16);
    const int rot = (seg & 3) * 2;
#pragma unroll 8
    for (int jj = 0; jj < NCH / 16; ++jj) {
        const float4 c = p2[j0 + ((jj + rot) & (NCH / 16 - 1))];
        float s1 = fmaf(c.x, m2x, c.w);
        s1 = fmaf(c.y, m2y, s1);
        s1 = fmaf(c.z, m2z, s1);
        m = fminf(m, s1);
    }
    pmin[q][seg] = m;
    __syncthreads();
    if (t < 16) {
        float mm = pmin[t][0];
#pragma unroll
        for (int s = 1; s < 16; ++s) mm = fminf(mm, pmin[t][s]);
        const float d = sqrtf(fmaxf(mm + qn_s[t], 0.f));
        const bool in = d < 0.1f;
        bsum[t] = in ? d   : 0.f;
        bcnt[t] = in ? 1.f : 0.f;
    }
    __syncthreads();
    if (t == 0) {
        double sc = 0.0, sn = 0.0;
        for (int i = 0; i < 16; ++i) { sc += (double)bsum[i]; sn += (double)bcnt[i]; }
        atomicAdd(&acc[3], sc);
        atomicAdd(&acc[4], sn);
    }
}

__global__ void fin_kernel(const double* __restrict__ acc, float* __restrict__ out) {
    if (threadIdx.x == 0) {
        const double recon  = acc[0] / (double)(NBATCH * NPTS * 3);
        const double percep = acc[1] / 4096.0;
        const double cont   = acc[2] / (double)(NBATCH * NPTS * KNN);
        const double cnt    = acc[4];
        const double bnd    = (cnt > 0.0) ? acc[3] / ((cnt > 1.0) ? cnt : 1.0) : 0.0;
        const double total  = 1.0 * recon + 0.5 * percep + 0.5 * cont + 1.0 * bnd;
        out[0] = (float)recon;
        out[1] = (float)percep;
        out[2] = (float)cont;
        out[3] = (float)bnd;
        out[4] = (float)total;
    }
}

extern "C" void kernel_launch(void* const* d_in, const int* in_sizes, int n_in,
                              void* d_out, int out_size, void* d_ws, size_t ws_size,
                              hipStream_t stream) {
    const float* pred = (const float*)d_in[0];
    const float* targ = (const float*)d_in[1];
    const float* pf   = (const float*)d_in[2];
    const float* tf   = (const float*)d_in[3];
    const float* c1   = (const float*)d_in[4];
    const float* c2   = (const float*)d_in[5];
    float* out  = (float*)d_out;
    double* acc = (double*)d_ws;

    hipMemsetAsync(acc, 0, 5 * sizeof(double), stream);
    hipLaunchKernelGGL(cont_kernel, dim3(NBATCH * (NPTS / QPB)), dim3(256), 0, stream,
                       pred, acc);
    hipLaunchKernelGGL(mse_kernel, dim3(112), dim3(256), 0, stream,
                       pred, targ, pf, tf, acc);
    hipLaunchKernelGGL(bnd_kernel, dim3(NCH / 16), dim3(256), 0, stream, c1, c2, acc);
    hipLaunchKernelGGL(fin_kernel, dim3(1), dim3(64), 0, stream, acc, out);
}

// Round 6
// 145.625 us; speedup vs baseline: 5.9091x; 1.1099x over previous
//
#include <hip/hip_runtime.h>
#include <math.h>

#define NBATCH 4
#define NPTS   8192
#define KNN    8
#define NCH    4096
#define SLICES 8
#define SLEN   (NPTS / SLICES)   // 1024 candidates per slice-wave

// ws layout (doubles): [0]=recon_sum [1]=percep_sum [2]=cont_sum [3]=bnd_sum [4]=bnd_cnt

// single-block insert: 8 instrs, bd pinned via tied "+v", in-place descending
// order reads only pre-block values => depth-1 sorted insert (ascending top-8).
#define INSERT8(bd, key)                                          \
    asm("v_med3_u32 %7, %8, %6, %7\n\t"                           \
        "v_med3_u32 %6, %8, %5, %6\n\t"                           \
        "v_med3_u32 %5, %8, %4, %5\n\t"                           \
        "v_med3_u32 %4, %8, %3, %4\n\t"                           \
        "v_med3_u32 %3, %8, %2, %3\n\t"                           \
        "v_med3_u32 %2, %8, %1, %2\n\t"                           \
        "v_med3_u32 %1, %8, %0, %1\n\t"                           \
        "v_min_u32  %0, %0, %8"                                   \
        : "+v"(bd[0]), "+v"(bd[1]), "+v"(bd[2]), "+v"(bd[3]),     \
          "+v"(bd[4]), "+v"(bd[5]), "+v"(bd[6]), "+v"(bd[7])      \
        : "v"(key))

// Fused MSE: blocks [0,96) -> recon (float4, 24576 exactly); [96,112) -> percep.
__global__ __launch_bounds__(256) void mse_kernel(const float* __restrict__ a,
                                                  const float* __restrict__ b,
                                                  const float* __restrict__ a2,
                                                  const float* __restrict__ b2,
                                                  double* __restrict__ acc) {
    const int t = threadIdx.x;
    const int blk = blockIdx.x;
    float s;
    int which;
    if (blk < 96) {
        which = 0;
        const int i = blk * 256 + t;
        const float4 va = reinterpret_cast<const float4*>(a)[i];
        const float4 vb = reinterpret_cast<const float4*>(b)[i];
        const float dx = va.x - vb.x, dy = va.y - vb.y;
        const float dz = va.z - vb.z, dw = va.w - vb.w;
        s = dx * dx + dy * dy + dz * dz + dw * dw;
    } else {
        which = 1;
        const int i = (blk - 96) * 256 + t;
        const float d = a2[i] - b2[i];
        s = d * d;
    }
#pragma unroll
    for (int o = 32; o > 0; o >>= 1) s += __shfl_down(s, o, 64);
    __shared__ float wsum[4];
    if ((t & 63) == 0) wsum[t >> 6] = s;
    __syncthreads();
    if (t == 0)
        atomicAdd(&acc[which], (double)(wsum[0] + wsum[1] + wsum[2] + wsum[3]));
}

// Continuity kNN, scalar-broadcast form: block = 8 waves; every wave holds the
// SAME 64 queries (one per lane) and scans its own 1024-candidate slice with
// wave-uniform scalar loads (no LDS, no per-lane VMEM in the hot loop).
// Key = f32 bits of exact (p-q)^2 (>=0) with low 13 bits replaced by index;
// self has d2==0 exactly -> key==qi, filtered at merge. Branchless med3 top-8.
__global__ __launch_bounds__(512, 8) void cont_kernel(const float* __restrict__ pts,
                                                      double* __restrict__ acc) {
    __shared__ unsigned mrg[SLICES][KNN][64];   // 16 KB, lane-consecutive
    const int t    = threadIdx.x;
    const int lane = t & 63;
    const int w    = __builtin_amdgcn_readfirstlane(t >> 6);   // slice id (SGPR)
    const int nqw  = NPTS / 64;                 // 128 query-waves per batch
    const int b    = blockIdx.x / nqw;
    const int q0   = (blockIdx.x % nqw) * 64;
    const int qi   = q0 + lane;
    const float* __restrict__ P = pts + (size_t)b * (NPTS * 3);

    const float qx = P[qi * 3 + 0];
    const float qy = P[qi * 3 + 1];
    const float qz = P[qi * 3 + 2];

    unsigned bd[KNN];
#pragma unroll
    for (int s = 0; s < KNN; ++s) bd[s] = 0xFFFFFFFFu;

    const float* __restrict__ S = P + w * (SLEN * 3);   // uniform base
    const unsigned jb = (unsigned)(w * SLEN);

#define CAND(CX, CY, CZ, JOFF)                                                \
    do {                                                                      \
        const float dx = (CX) - qx, dy = (CY) - qy, dz = (CZ) - qz;           \
        const float d2 = fmaf(dx, dx, fmaf(dy, dy, dz * dz));                 \
        const unsigned key =                                                  \
            (__float_as_uint(d2) & 0xFFFFE000u) | (jb + (unsigned)(JOFF));    \
        INSERT8(bd, key);                                                     \
    } while (0)

#pragma unroll 4
    for (int j4 = 0; j4 < SLEN; j4 += 4) {
        // 4 candidates = 12 uniform floats (48B-aligned)
        const float4 u0 = *reinterpret_cast<const float4*>(S + j4 * 3 + 0);
        const float4 u1 = *reinterpret_cast<const float4*>(S + j4 * 3 + 4);
        const float4 u2 = *reinterpret_cast<const float4*>(S + j4 * 3 + 8);
        CAND(u0.x, u0.y, u0.z, j4 + 0);
        CAND(u0.w, u1.x, u1.y, j4 + 1);
        CAND(u1.z, u1.w, u2.x, j4 + 2);
        CAND(u2.y, u2.z, u2.w, j4 + 3);
    }
#undef CAND

#pragma unroll
    for (int s = 0; s < KNN; ++s) mrg[w][s][lane] = bd[s];
    __syncthreads();

    if (w == 0) {   // wave 0 merges all 8 slices; one query per lane
        const unsigned selfidx = (unsigned)qi;
        unsigned best[KNN];
#pragma unroll
        for (int s = 0; s < KNN; ++s) best[s] = 0xFFFFFFFFu;
        for (int sl = 0; sl < SLICES; ++sl) {
#pragma unroll
            for (int u = 0; u < KNN; ++u) {
                unsigned key = mrg[sl][u][lane];
                key = ((key & 0x1FFFu) == selfidx) ? 0xFFFFFFFFu : key;  // drop self
                INSERT8(best, key);
            }
        }
        float px[KNN], py[KNN], pz[KNN];
        float sx = 0.f, sy = 0.f, sz = 0.f;
#pragma unroll
        for (int s = 0; s < KNN; ++s) {
            const int j = (int)(best[s] & 0x1FFFu);
            px[s] = P[j * 3 + 0]; py[s] = P[j * 3 + 1]; pz[s] = P[j * 3 + 2];
            sx += px[s]; sy += py[s]; sz += pz[s];
        }
        const float cx = sx * (1.f / KNN), cy = sy * (1.f / KNN), cz = sz * (1.f / KNN);
        float ssum = 0.f;
#pragma unroll
        for (int s = 0; s < KNN; ++s) {
            const float dx = px[s] - cx, dy = py[s] - cy, dz = pz[s] - cz;
            ssum += dx * dx + dy * dy + dz * dz;
        }
#pragma unroll
        for (int o = 32; o > 0; o >>= 1) ssum += __shfl_down(ssum, o, 64);
        if (lane == 0) atomicAdd(&acc[2], (double)ssum);
    }
}

// Boundary: grid 256 x 256 thr; 16 queries x 16 segs of 256 j's per block.
// chunk2 staged as float4 (x,y,z,|p|^2); min over (|p|^2 - 2p.q), |q|^2 added once.
// Per-seg rotated start (+2*(seg&3)) de-conflicts the 4 seg-groups' LDS reads.
__global__ __launch_bounds__(256) void bnd_kernel(const float* __restrict__ c1,
                                                  const float* __restrict__ c2,
                                                  double* __restrict__ acc) {
    __shared__ float4 p2[NCH];          // 64 KB
    __shared__ float qn_s[16];
    __shared__ float pmin[16][17];
    __shared__ float bsum[16], bcnt[16];
    const int t = threadIdx.x;
#pragma unroll
    for (int r = 0; r < 16; ++r) {
        const int idx = t + 256 * r;
        const float x = c2[idx * 3 + 0];
        const float y = c2[idx * 3 + 1];
        const float z = c2[idx * 3 + 2];
        p2[idx] = make_float4(x, y, z, x * x + y * y + z * z);
    }
    const int q   = t & 15;
    const int seg = t >> 4;
    const int qi  = blockIdx.x * 16 + q;
    const float qx = c1[qi * 3 + 0];
    const float qy = c1[qi * 3 + 1];
    const float qz = c1[qi * 3 + 2];
    const float m2x = -2.f * qx, m2y = -2.f * qy, m2z = -2.f * qz;
    if (seg == 0) qn_s[q] = qx * qx + qy * qy + qz * qz;
    __syncthreads();

    float m = 3.0e38f;
    const int j0  = seg * (NCH / 16);
    const int rot = (seg & 3) * 2;
#pragma unroll 8
    for (int jj = 0; jj < NCH / 16; ++jj) {
        const float4 c = p2[j0 + ((jj + rot) & (NCH / 16 - 1))];
        float s1 = fmaf(c.x, m2x, c.w);
        s1 = fmaf(c.y, m2y, s1);
        s1 = fmaf(c.z, m2z, s1);
        m = fminf(m, s1);
    }
    pmin[q][seg] = m;
    __syncthreads();
    if (t < 16) {
        float mm = pmin[t][0];
#pragma unroll
        for (int s = 1; s < 16; ++s) mm = fminf(mm, pmin[t][s]);
        const float d = sqrtf(fmaxf(mm + qn_s[t], 0.f));
        const bool in = d < 0.1f;
        bsum[t] = in ? d   : 0.f;
        bcnt[t] = in ? 1.f : 0.f;
    }
    __syncthreads();
    if (t == 0) {
        double sc = 0.0, sn = 0.0;
        for (int i = 0; i < 16; ++i) { sc += (double)bsum[i]; sn += (double)bcnt[i]; }
        atomicAdd(&acc[3], sc);
        atomicAdd(&acc[4], sn);
    }
}

__global__ void fin_kernel(const double* __restrict__ acc, float* __restrict__ out) {
    if (threadIdx.x == 0) {
        const double recon  = acc[0] / (double)(NBATCH * NPTS * 3);
        const double percep = acc[1] / 4096.0;
        const double cont   = acc[2] / (double)(NBATCH * NPTS * KNN);
        const double cnt    = acc[4];
        const double bnd    = (cnt > 0.0) ? acc[3] / ((cnt > 1.0) ? cnt : 1.0) : 0.0;
        const double total  = 1.0 * recon + 0.5 * percep + 0.5 * cont + 1.0 * bnd;
        out[0] = (float)recon;
        out[1] = (float)percep;
        out[2] = (float)cont;
        out[3] = (float)bnd;
        out[4] = (float)total;
    }
}

extern "C" void kernel_launch(void* const* d_in, const int* in_sizes, int n_in,
                              void* d_out, int out_size, void* d_ws, size_t ws_size,
                              hipStream_t stream) {
    const float* pred = (const float*)d_in[0];
    const float* targ = (const float*)d_in[1];
    const float* pf   = (const float*)d_in[2];
    const float* tf   = (const float*)d_in[3];
    const float* c1   = (const float*)d_in[4];
    const float* c2   = (const float*)d_in[5];
    float* out  = (float*)d_out;
    double* acc = (double*)d_ws;

    hipMemsetAsync(acc, 0, 5 * sizeof(double), stream);
    hipLaunchKernelGGL(cont_kernel, dim3(NBATCH * (NPTS / 64)), dim3(512), 0, stream,
                       pred, acc);
    hipLaunchKernelGGL(mse_kernel, dim3(112), dim3(256), 0, stream,
                       pred, targ, pf, tf, acc);
    hipLaunchKernelGGL(bnd_kernel, dim3(NCH / 16), dim3(256), 0, stream, c1, c2, acc);
    hipLaunchKernelGGL(fin_kernel, dim3(1), dim3(64), 0, stream, acc, out);
}